// Round 1
// baseline (12546.254 us; speedup 1.0000x reference)
//
#include <hip/hip_runtime.h>

static constexpr int Bt = 32;
static constexpr int SEQ = 336, PRED = 336, CIN = 7, ALLT = 672;
static constexpr int DM = 64, NFFT = 64, HOP = 8, NF = 85;
static constexpr int MARK = 4;
static constexpr float INV3 = 1.0f / 3.0f;

// ---------------- K1: per (b,c) mean / std over time ----------------
__global__ __launch_bounds__(64) void k_stats(const float* __restrict__ x,
                                              float* __restrict__ mean,
                                              float* __restrict__ stdv) {
    int bc = blockIdx.x;              // b*7+c
    int b = bc / CIN, c = bc % CIN;
    int lane = threadIdx.x;
    float s = 0.f, s2 = 0.f;
    for (int t = lane; t < SEQ; t += 64) {
        float v = x[(b * SEQ + t) * CIN + c];
        s += v; s2 += v * v;
    }
    for (int m = 32; m >= 1; m >>= 1) { s += __shfl_xor(s, m); s2 += __shfl_xor(s2, m); }
    if (lane == 0) {
        float mu = s / SEQ;
        float var = s2 / SEQ - mu * mu;
        mean[bc] = mu;
        stdv[bc] = sqrtf(var + 1e-5f);
    }
}

// ---------------- K2: embedding (token conv + temporal + PE) ----------------
__global__ __launch_bounds__(256) void k_embed(const float* __restrict__ x,
                                               const float* __restrict__ mark,
                                               const float* __restrict__ tok_w,
                                               const float* __restrict__ temp_w,
                                               const float* __restrict__ mean,
                                               const float* __restrict__ stdv,
                                               float* __restrict__ enc0) {
    int i = blockIdx.x * 256 + threadIdx.x;
    if (i >= Bt * SEQ * DM) return;
    int d = i & 63;
    int t = (i >> 6) % SEQ;
    int b = i / (SEQ * DM);
    float val = 0.f;
    for (int c = 0; c < CIN; ++c) {
        float mu = mean[b * CIN + c];
        float is = 1.f / stdv[b * CIN + c];
        for (int j = 0; j < 3; ++j) {
            int tt = t + j - 1;
            if (tt < 0) tt += SEQ;
            if (tt >= SEQ) tt -= SEQ;
            float xv = (x[(b * SEQ + tt) * CIN + c] - mu) * is;
            val += xv * tok_w[(d * CIN + c) * 3 + j];
        }
    }
    float mk = 0.f;
    for (int m = 0; m < MARK; ++m) mk += mark[(b * SEQ + t) * MARK + m] * temp_w[d * MARK + m];
    float div = expf(-(float)(d & ~1) * (9.210340371976184f / (float)DM));
    float arg = (float)t * div;
    float pe = (d & 1) ? cosf(arg) : sinf(arg);
    enc0[i] = val + mk + pe;
}

// ---------------- K3: predict_linear (time 336 -> 672) ----------------
__global__ __launch_bounds__(256) void k_plin(const float* __restrict__ enc0,
                                              const float* __restrict__ pl_w,
                                              const float* __restrict__ pl_b,
                                              float* __restrict__ enc) {
    int i = blockIdx.x * 256 + threadIdx.x;
    if (i >= Bt * ALLT * DM) return;
    int d = i & 63;
    int a = (i >> 6) % ALLT;
    int b = i / (ALLT * DM);
    float acc = pl_b[a];
    const float* e0 = enc0 + (size_t)b * SEQ * DM + d;
    const float* w = pl_w + (size_t)a * SEQ;
    for (int t = 0; t < SEQ; ++t) acc += e0[t * DM] * w[t];
    enc[i] = acc;
}

// ---------------- K4: STFT (reflect pad + hann + DFT64, ortho) ----------------
__global__ __launch_bounds__(256) void k_stft(const float* __restrict__ enc, int b0,
                                              float* __restrict__ Sr, float* __restrict__ Si) {
    __shared__ float xp[ALLT + NFFT];   // 736
    __shared__ float twc[64], tws[64];
    __shared__ float xw[NF * 65];       // padded ld=65 (bank-conflict-free)
    int bl = blockIdx.x >> 6;
    int n = blockIdx.x & 63;
    int bg = b0 + bl;
    int t = threadIdx.x;
    for (int i = t; i < ALLT + NFFT; i += 256) {
        int j = i - 32;
        if (j < 0) j = -j;
        if (j > ALLT - 1) j = 2 * (ALLT - 1) - j;
        xp[i] = enc[((size_t)bg * ALLT + j) * DM + n];
    }
    if (t < 64) {
        float ang = (6.283185307179586f / 64.f) * (float)t;
        twc[t] = cosf(ang);
        tws[t] = sinf(ang);
    }
    __syncthreads();
    for (int i = t; i < NF * NFFT; i += 256) {
        int f = i >> 6, tt = i & 63;
        float win = (0.5f - 0.5f * twc[tt]) * 0.125f;  // hann * 1/sqrt(64)
        xw[f * 65 + tt] = xp[f * HOP + tt] * win;
    }
    __syncthreads();
    size_t base = (size_t)(bl * 64 + n) * NFFT * NF;
    for (int i = t; i < NFFT * NF; i += 256) {
        int k = i / NF, f = i % NF;
        float ar = 0.f, ai = 0.f;
        for (int tt = 0; tt < 64; ++tt) {
            float v = xw[f * 65 + tt];
            int m = (k * tt) & 63;
            ar += v * twc[m];
            ai -= v * tws[m];
        }
        Sr[base + (size_t)k * NF + f] = ar;
        Si[base + (size_t)k * NF + f] = ai;
    }
}

// ---------------- K5: qk = S S^T (complex), sigmoid gate, a = g S ----------------
__global__ __launch_bounds__(256) void k_qka(const float* __restrict__ Sr,
                                             const float* __restrict__ Si,
                                             float* __restrict__ Ar,
                                             float* __restrict__ Ai) {
    __shared__ float sr[DM * NF], si[DM * NF];  // 5440 each
    __shared__ float gr[DM * DM], gi[DM * DM];  // 4096 each
    int bn = blockIdx.x;
    int t = threadIdx.x;
    size_t base = (size_t)bn * DM * NF;
    for (int i = t; i < DM * NF; i += 256) { sr[i] = Sr[base + i]; si[i] = Si[base + i]; }
    __syncthreads();
    for (int e = t; e < DM * DM; e += 256) {
        int x = e >> 6, y = e & 63;
        const float* pxr = sr + x * NF;
        const float* pxi = si + x * NF;
        const float* pyr = sr + y * NF;
        const float* pyi = si + y * NF;
        float qr = 0.f, qi = 0.f;
        for (int f = 0; f < NF; ++f) {
            float xr = pxr[f], xi = pxi[f], yr = pyr[f], yi = pyi[f];
            qr += xr * yr - xi * yi;
            qi += xr * yi + xi * yr;
        }
        gr[e] = 1.f / (1.f + __expf(-qr));
        gi[e] = 1.f / (1.f + __expf(-qi));
    }
    __syncthreads();
    for (int e = t; e < DM * NF; e += 256) {
        int x = e / NF, f = e % NF;
        const float* pgr = gr + x * 64;
        const float* pgi = gi + x * 64;
        float ar = 0.f, ai = 0.f;
        for (int y = 0; y < 64; ++y) {
            float syr = sr[y * NF + f], syi = si[y * NF + f];
            float g1 = pgr[y], g2 = pgi[y];
            ar += g1 * syr - g2 * syi;
            ai += g1 * syi + g2 * syr;
        }
        Ar[base + e] = ar;
        Ai[base + e] = ai;
    }
}

// ---------------- K6: complex 1x1 conv (c0) + relu + combine into yfull ----------------
__global__ __launch_bounds__(256) void k_c0(const float* __restrict__ Ar,
                                            const float* __restrict__ Ai,
                                            const float* __restrict__ wr,
                                            const float* __restrict__ wi,
                                            const float* __restrict__ br,
                                            const float* __restrict__ bi,
                                            const float* __restrict__ l0w,
                                            float* __restrict__ yfull) {
    __shared__ float lr[DM * NF], li[DM * NF];
    int b = blockIdx.x >> 6, x = blockIdx.x & 63;
    int t = threadIdx.x;
    for (int i = t; i < DM * NF; i += 256) {
        int ci = i / NF, f = i % NF;
        size_t src = ((size_t)(b * 64 + ci) * 64 + x) * NF + f;
        lr[i] = Ar[src];
        li[i] = Ai[src];
    }
    __syncthreads();
    float w0 = l0w[0], w1 = l0w[1];
    int co = t >> 2, yg = t & 3;
    float accr[22], acci[22];
#pragma unroll
    for (int j = 0; j < 22; ++j) { accr[j] = 0.f; acci[j] = 0.f; }
    for (int ci = 0; ci < 64; ++ci) {
        float wwr = wr[co * 64 + ci], wwi = wi[co * 64 + ci];
        const float* pr = lr + ci * NF;
        const float* pi = li + ci * NF;
#pragma unroll
        for (int j = 0; j < 22; ++j) {
            int f = yg + 4 * j;
            if (f < NF) {
                float xr = pr[f], xi = pi[f];
                accr[j] += xr * wwr - xi * wwi;
                acci[j] += xi * wwr + xr * wwi;
            }
        }
    }
    float bbr = br[co] - bi[co];
    float bbi = br[co] + bi[co];
    size_t obase = ((size_t)(b * 64 + co) * 64 + x) * NF;
    for (int j = 0; j < 22; ++j) {
        int f = yg + 4 * j;
        if (f < NF) {
            float yr = fmaxf(accr[j] + bbr, 0.f);
            float yi = fmaxf(acci[j] + bbi, 0.f);
            yfull[obase + f] = (yr * w0 + yi * w1) * INV3;
        }
    }
}

// ---------------- K7: complex 3x3 dilated conv ----------------
// mode 0: write h (bias only);  mode 1: relu+combine, accumulate into yfull
__global__ __launch_bounds__(256) void k_conv3(const float* __restrict__ in_r,
                                               const float* __restrict__ in_i,
                                               const float* __restrict__ w_r,
                                               const float* __restrict__ w_i,
                                               const float* __restrict__ b_r,
                                               const float* __restrict__ b_i,
                                               int K, int mode,
                                               const float* __restrict__ l0w,
                                               float* __restrict__ out_r,
                                               float* __restrict__ out_i) {
    __shared__ float lr[3 * 16 * 100], li[3 * 16 * 100];
    int b = blockIdx.x >> 6, x0 = blockIdx.x & 63;
    int t = threadIdx.x;
    int cog = t >> 4, fg = t & 15;
    int co0 = cog * 4;
    float accr[4][6], acci[4][6];
#pragma unroll
    for (int c = 0; c < 4; ++c)
#pragma unroll
        for (int j = 0; j < 6; ++j) { accr[c][j] = 0.f; acci[c][j] = 0.f; }

    for (int chunk = 0; chunk < 4; ++chunk) {
        __syncthreads();
        for (int i = t; i < 3 * 16 * 100; i += 256) {
            int u = i / 1600;
            int r2 = i % 1600;
            int cil = r2 / 100;
            int p = r2 % 100;
            int f = p - K;
            int xr = x0 + (u - 1) * K;
            int ci = chunk * 16 + cil;
            bool ok = (f >= 0 && f < NF && xr >= 0 && xr < 64);
            size_t src = ((size_t)(b * 64 + ci) * 64 + xr) * NF + f;
            lr[i] = ok ? in_r[src] : 0.f;
            li[i] = ok ? in_i[src] : 0.f;
        }
        __syncthreads();
        for (int cil = 0; cil < 16; ++cil) {
            int ci = chunk * 16 + cil;
#pragma unroll
            for (int u = 0; u < 3; ++u) {
                const float* rowr = lr + (u * 16 + cil) * 100;
                const float* rowi = li + (u * 16 + cil) * 100;
                float xr_[6][3], xi_[6][3];
#pragma unroll
                for (int j = 0; j < 6; ++j)
#pragma unroll
                    for (int v = 0; v < 3; ++v) {
                        int p = fg + 16 * j + v * K;
                        xr_[j][v] = rowr[p];
                        xi_[j][v] = rowi[p];
                    }
#pragma unroll
                for (int c = 0; c < 4; ++c) {
                    int co = co0 + c;
                    const float* wpr = w_r + ((size_t)(co * 64 + ci)) * 9 + u * 3;
                    const float* wpi = w_i + ((size_t)(co * 64 + ci)) * 9 + u * 3;
                    float wr0 = wpr[0], wr1 = wpr[1], wr2 = wpr[2];
                    float wi0 = wpi[0], wi1 = wpi[1], wi2 = wpi[2];
#pragma unroll
                    for (int j = 0; j < 6; ++j) {
                        accr[c][j] += xr_[j][0] * wr0 - xi_[j][0] * wi0
                                    + xr_[j][1] * wr1 - xi_[j][1] * wi1
                                    + xr_[j][2] * wr2 - xi_[j][2] * wi2;
                        acci[c][j] += xi_[j][0] * wr0 + xr_[j][0] * wi0
                                    + xi_[j][1] * wr1 + xr_[j][1] * wi1
                                    + xi_[j][2] * wr2 + xr_[j][2] * wi2;
                    }
                }
            }
        }
    }
    float w0 = 0.f, w1 = 0.f;
    if (mode == 1) { w0 = l0w[0]; w1 = l0w[1]; }
#pragma unroll
    for (int c = 0; c < 4; ++c) {
        int co = co0 + c;
        float bbr = b_r[co] - b_i[co];
        float bbi = b_r[co] + b_i[co];
        size_t obase = ((size_t)(b * 64 + co) * 64 + x0) * NF;
        for (int j = 0; j < 6; ++j) {
            int f = fg + 16 * j;
            if (f < NF) {
                float vr = accr[c][j] + bbr;
                float vi = acci[c][j] + bbi;
                if (mode == 0) {
                    out_r[obase + f] = vr;
                    out_i[obase + f] = vi;
                } else {
                    out_r[obase + f] += (fmaxf(vr, 0.f) * w0 + fmaxf(vi, 0.f) * w1) * INV3;
                }
            }
        }
    }
}

// ---------------- K8: mean over freq axis + l0 bias ----------------
__global__ __launch_bounds__(256) void k_reduce(const float* __restrict__ yfull,
                                                const float* __restrict__ l0b,
                                                float* __restrict__ y2, int bc) {
    int i = blockIdx.x * 256 + threadIdx.x;
    if (i >= bc * DM * NF) return;
    int f = i % NF;
    int rest = i / NF;
    int n = rest & 63;
    int b = rest >> 6;
    float s = 0.f;
    const float* p = yfull + ((size_t)(b * 64 + n) * 64) * NF + f;
    for (int x = 0; x < 64; ++x) s += p[x * NF];
    y2[i] = s * (1.f / 64.f) + l0b[0];
}

// ---------------- K9: l2 (NF->ALL) + transpose + LayerNorm ----------------
__global__ __launch_bounds__(64) void k_l2ln(const float* __restrict__ y2,
                                             const float* __restrict__ l2w,
                                             const float* __restrict__ l2b,
                                             const float* __restrict__ g,
                                             const float* __restrict__ be,
                                             float* __restrict__ enc, int b0) {
    int bl = blockIdx.x / ALLT;
    int a = blockIdx.x % ALLT;
    int d = threadIdx.x;
    const float* wp = l2w + (size_t)a * NF;
    const float* yp = y2 + (size_t)(bl * 64 + d) * NF;
    float acc = l2b[a];
    for (int f = 0; f < NF; ++f) acc += yp[f] * wp[f];
    float s = acc, s2 = acc * acc;
    for (int m = 32; m >= 1; m >>= 1) { s += __shfl_xor(s, m); s2 += __shfl_xor(s2, m); }
    float mu = s * (1.f / 64.f);
    float var = s2 * (1.f / 64.f) - mu * mu;
    float rs = rsqrtf(var + 1e-5f);
    enc[((size_t)(b0 + bl) * ALLT + a) * DM + d] = (acc - mu) * rs * g[d] + be[d];
}

// ---------------- K10: T[b,ci,j] = sum_hx enc[b,ci,2hx+j-1]*l1w[hx] ----------------
__global__ __launch_bounds__(256) void k_T(const float* __restrict__ enc,
                                           const float* __restrict__ l1w,
                                           float* __restrict__ T) {
    int i = blockIdx.x * 256 + threadIdx.x;
    if (i >= Bt * ALLT * 3) return;
    int j = i % 3;
    int rest = i / 3;
    int ci = rest % ALLT;
    int b = rest / ALLT;
    const float* e = enc + ((size_t)b * ALLT + ci) * DM;
    float s = 0.f;
    for (int hx = 0; hx < 32; ++hx) {
        int p = 2 * hx + j - 1;
        if (p >= 0 && p < DM) s += e[p] * l1w[hx];
    }
    T[i] = s;
}

// ---------------- K11: seq_series[b,co] ----------------
__global__ __launch_bounds__(256) void k_seq(const float* __restrict__ T,
                                             const float* __restrict__ cvw,
                                             const float* __restrict__ cvb,
                                             const float* __restrict__ l1w,
                                             const float* __restrict__ l1b,
                                             float* __restrict__ out) {
    int i = blockIdx.x * 256 + threadIdx.x;
    if (i >= Bt * ALLT) return;
    int co = i % ALLT;
    int b = i / ALLT;
    float sl1 = 0.f;
    for (int hx = 0; hx < 32; ++hx) sl1 += l1w[hx];
    const float* tp = T + (size_t)b * ALLT * 3;
    const float* wp = cvw + (size_t)co * ALLT * 3;
    float s = 0.f;
    for (int q = 0; q < ALLT * 3; ++q) s += tp[q] * wp[q];
    out[i] = s + cvb[co] * sl1 + l1b[0];
}

// ---------------- K12: projection + denorm, last PRED steps ----------------
__global__ __launch_bounds__(256) void k_dec(const float* __restrict__ enc,
                                             const float* __restrict__ pw,
                                             const float* __restrict__ pb,
                                             const float* __restrict__ mean,
                                             const float* __restrict__ stdv,
                                             float* __restrict__ out) {
    int i = blockIdx.x * 256 + threadIdx.x;
    if (i >= Bt * PRED * CIN) return;
    int c = i % CIN;
    int rest = i / CIN;
    int tt = rest % PRED;
    int b = rest / PRED;
    const float* e = enc + ((size_t)b * ALLT + SEQ + tt) * DM;
    const float* w = pw + c * DM;
    float s = pb[c];
    for (int d = 0; d < DM; ++d) s += e[d] * w[d];
    out[i] = s * stdv[b * CIN + c] + mean[b * CIN + c];
}

extern "C" void kernel_launch(void* const* d_in, const int* in_sizes, int n_in,
                              void* d_out, int out_size, void* d_ws, size_t ws_size,
                              hipStream_t stream) {
    (void)in_sizes; (void)n_in; (void)out_size;
    const float* x_enc  = (const float*)d_in[0];
    const float* x_mark = (const float*)d_in[1];
    const float* tok_w  = (const float*)d_in[4];
    const float* temp_w = (const float*)d_in[5];
    const float* pl_w   = (const float*)d_in[6];
    const float* pl_b   = (const float*)d_in[7];
    const float* ln_g   = (const float*)d_in[8];
    const float* ln_b   = (const float*)d_in[9];
    const float* c0_wr  = (const float*)d_in[10];
    const float* c0_wi  = (const float*)d_in[11];
    const float* c0_br  = (const float*)d_in[12];
    const float* c0_bi  = (const float*)d_in[13];
    const float* cA_wr  = (const float*)d_in[14];
    const float* cA_wi  = (const float*)d_in[15];
    const float* cA_br  = (const float*)d_in[16];
    const float* cA_bi  = (const float*)d_in[17];
    const float* cB_wr  = (const float*)d_in[18];
    const float* cB_wi  = (const float*)d_in[19];
    const float* cB_br  = (const float*)d_in[20];
    const float* cB_bi  = (const float*)d_in[21];
    const float* l0_w   = (const float*)d_in[22];
    const float* l0_b   = (const float*)d_in[23];
    const float* l2_w   = (const float*)d_in[24];
    const float* l2_b   = (const float*)d_in[25];
    const float* cv_w   = (const float*)d_in[26];
    const float* cv_b   = (const float*)d_in[27];
    const float* l1_w   = (const float*)d_in[28];
    const float* l1_b   = (const float*)d_in[29];
    const float* proj_w = (const float*)d_in[30];
    const float* proj_b = (const float*)d_in[31];

    float* out0 = (float*)d_out;                    // dec: [32,336,7]
    float* out1 = out0 + (size_t)Bt * PRED * CIN;   // seq_series: [32,672]

    float* ws = (float*)d_ws;
    size_t off = 0;
    float* enc  = ws + off; off += (size_t)Bt * ALLT * DM;   // 1,376,256
    float* enc0 = ws + off; off += (size_t)Bt * SEQ * DM;    // 688,128 (reused as T)
    float* mean = ws + off; off += 256;
    float* stdv = ws + off; off += 256;

    const size_t perb = (size_t)DM * NFFT * NF;  // 348,160
    int Bc = 32;
    while (Bc > 1) {
        size_t need = (off + (size_t)Bc * DM * NF + 5 * (size_t)Bc * perb) * sizeof(float);
        if (need <= ws_size) break;
        Bc >>= 1;
    }
    float* y2 = ws + off; off += (size_t)Bc * DM * NF;
    float* Sr = ws + off; off += (size_t)Bc * perb;
    float* Si = ws + off; off += (size_t)Bc * perb;
    float* Ar = ws + off; off += (size_t)Bc * perb;
    float* Ai = ws + off; off += (size_t)Bc * perb;
    float* yfull = ws + off; off += (size_t)Bc * perb;
    float* Hr = Sr;  // reuse: S dead after k_qka
    float* Hi = Si;
    float* Tb = enc0;  // reuse: enc0 dead after k_plin

    k_stats<<<Bt * CIN, 64, 0, stream>>>(x_enc, mean, stdv);
    k_embed<<<(Bt * SEQ * DM + 255) / 256, 256, 0, stream>>>(x_enc, x_mark, tok_w, temp_w,
                                                             mean, stdv, enc0);
    k_plin<<<(Bt * ALLT * DM + 255) / 256, 256, 0, stream>>>(enc0, pl_w, pl_b, enc);

    for (int l = 0; l < 2; ++l) {
        for (int b0 = 0; b0 < Bt; b0 += Bc) {
            k_stft<<<Bc * 64, 256, 0, stream>>>(enc, b0, Sr, Si);
            k_qka<<<Bc * 64, 256, 0, stream>>>(Sr, Si, Ar, Ai);
            k_c0<<<Bc * 64, 256, 0, stream>>>(Ar, Ai, c0_wr + (size_t)l * 4096,
                                              c0_wi + (size_t)l * 4096, c0_br + l * 64,
                                              c0_bi + l * 64, l0_w + l * 2, yfull);
            for (int k = 1; k <= 2; ++k) {
                size_t woff = ((size_t)l * 2 + (k - 1)) * 64 * 64 * 9;
                size_t boff = ((size_t)l * 2 + (k - 1)) * 64;
                k_conv3<<<Bc * 64, 256, 0, stream>>>(Ar, Ai, cA_wr + woff, cA_wi + woff,
                                                     cA_br + boff, cA_bi + boff, k, 0,
                                                     l0_w + l * 2, Hr, Hi);
                k_conv3<<<Bc * 64, 256, 0, stream>>>(Hr, Hi, cB_wr + woff, cB_wi + woff,
                                                     cB_br + boff, cB_bi + boff, k, 1,
                                                     l0_w + l * 2, yfull, Hi);
            }
            k_reduce<<<(Bc * DM * NF + 255) / 256, 256, 0, stream>>>(yfull, l0_b + l, y2, Bc);
            k_l2ln<<<Bc * ALLT, 64, 0, stream>>>(y2, l2_w + (size_t)l * ALLT * NF,
                                                 l2_b + (size_t)l * ALLT, ln_g, ln_b, enc, b0);
        }
    }

    k_T<<<(Bt * ALLT * 3 + 255) / 256, 256, 0, stream>>>(enc, l1_w, Tb);
    k_seq<<<(Bt * ALLT + 255) / 256, 256, 0, stream>>>(Tb, cv_w, cv_b, l1_w, l1_b, out1);
    k_dec<<<(Bt * PRED * CIN + 255) / 256, 256, 0, stream>>>(enc, proj_w, proj_b, mean, stdv, out0);
}

// Round 2
// 2985.134 us; speedup vs baseline: 4.2029x; 4.2029x over previous
//
#include <hip/hip_runtime.h>

typedef __attribute__((ext_vector_type(8))) short short8v;
typedef __attribute__((ext_vector_type(4))) float f32x4;

static constexpr int Bt = 32;
static constexpr int SEQ = 336, PRED = 336, CIN = 7, ALLT = 672;
static constexpr int DM = 64, NFFT = 64, HOP = 8, NF = 85;
static constexpr int MARK = 4;
static constexpr float INV3 = 1.0f / 3.0f;

__device__ inline short f2bf(float v) {
    unsigned u = __float_as_uint(v);
    u += 0x7fffu + ((u >> 16) & 1u);   // round-to-nearest-even
    return (short)(u >> 16);
}

// ---------------- K1: per (b,c) mean / std over time ----------------
__global__ __launch_bounds__(64) void k_stats(const float* __restrict__ x,
                                              float* __restrict__ mean,
                                              float* __restrict__ stdv) {
    int bc = blockIdx.x;              // b*7+c
    int b = bc / CIN, c = bc % CIN;
    int lane = threadIdx.x;
    float s = 0.f, s2 = 0.f;
    for (int t = lane; t < SEQ; t += 64) {
        float v = x[(b * SEQ + t) * CIN + c];
        s += v; s2 += v * v;
    }
    for (int m = 32; m >= 1; m >>= 1) { s += __shfl_xor(s, m); s2 += __shfl_xor(s2, m); }
    if (lane == 0) {
        float mu = s / SEQ;
        float var = s2 / SEQ - mu * mu;
        mean[bc] = mu;
        stdv[bc] = sqrtf(var + 1e-5f);
    }
}

// ---------------- K2: embedding (token conv + temporal + PE) ----------------
__global__ __launch_bounds__(256) void k_embed(const float* __restrict__ x,
                                               const float* __restrict__ mark,
                                               const float* __restrict__ tok_w,
                                               const float* __restrict__ temp_w,
                                               const float* __restrict__ mean,
                                               const float* __restrict__ stdv,
                                               float* __restrict__ enc0) {
    int i = blockIdx.x * 256 + threadIdx.x;
    if (i >= Bt * SEQ * DM) return;
    int d = i & 63;
    int t = (i >> 6) % SEQ;
    int b = i / (SEQ * DM);
    float val = 0.f;
    for (int c = 0; c < CIN; ++c) {
        float mu = mean[b * CIN + c];
        float is = 1.f / stdv[b * CIN + c];
        for (int j = 0; j < 3; ++j) {
            int tt = t + j - 1;
            if (tt < 0) tt += SEQ;
            if (tt >= SEQ) tt -= SEQ;
            float xv = (x[(b * SEQ + tt) * CIN + c] - mu) * is;
            val += xv * tok_w[(d * CIN + c) * 3 + j];
        }
    }
    float mk = 0.f;
    for (int m = 0; m < MARK; ++m) mk += mark[(b * SEQ + t) * MARK + m] * temp_w[d * MARK + m];
    float div = expf(-(float)(d & ~1) * (9.210340371976184f / (float)DM));
    float arg = (float)t * div;
    float pe = (d & 1) ? cosf(arg) : sinf(arg);
    enc0[i] = val + mk + pe;
}

// ---------------- K3: predict_linear (time 336 -> 672) ----------------
__global__ __launch_bounds__(256) void k_plin(const float* __restrict__ enc0,
                                              const float* __restrict__ pl_w,
                                              const float* __restrict__ pl_b,
                                              float* __restrict__ enc) {
    int i = blockIdx.x * 256 + threadIdx.x;
    if (i >= Bt * ALLT * DM) return;
    int d = i & 63;
    int a = (i >> 6) % ALLT;
    int b = i / (ALLT * DM);
    float acc = pl_b[a];
    const float* e0 = enc0 + (size_t)b * SEQ * DM + d;
    const float* w = pl_w + (size_t)a * SEQ;
    for (int t = 0; t < SEQ; ++t) acc += e0[t * DM] * w[t];
    enc[i] = acc;
}

// ---------------- K4: STFT (reflect pad + hann + DFT64, ortho) ----------------
__global__ __launch_bounds__(256) void k_stft(const float* __restrict__ enc, int b0,
                                              float* __restrict__ Sr, float* __restrict__ Si) {
    __shared__ float xp[ALLT + NFFT];   // 736
    __shared__ float twc[64], tws[64];
    __shared__ float xw[NF * 65];       // padded ld=65 (bank-conflict-free)
    int bl = blockIdx.x >> 6;
    int n = blockIdx.x & 63;
    int bg = b0 + bl;
    int t = threadIdx.x;
    for (int i = t; i < ALLT + NFFT; i += 256) {
        int j = i - 32;
        if (j < 0) j = -j;
        if (j > ALLT - 1) j = 2 * (ALLT - 1) - j;
        xp[i] = enc[((size_t)bg * ALLT + j) * DM + n];
    }
    if (t < 64) {
        float ang = (6.283185307179586f / 64.f) * (float)t;
        twc[t] = cosf(ang);
        tws[t] = sinf(ang);
    }
    __syncthreads();
    for (int i = t; i < NF * NFFT; i += 256) {
        int f = i >> 6, tt = i & 63;
        float win = (0.5f - 0.5f * twc[tt]) * 0.125f;  // hann * 1/sqrt(64)
        xw[f * 65 + tt] = xp[f * HOP + tt] * win;
    }
    __syncthreads();
    size_t base = (size_t)(bl * 64 + n) * NFFT * NF;
    for (int i = t; i < NFFT * NF; i += 256) {
        int k = i / NF, f = i % NF;
        float ar = 0.f, ai = 0.f;
        for (int tt = 0; tt < 64; ++tt) {
            float v = xw[f * 65 + tt];
            int m = (k * tt) & 63;
            ar += v * twc[m];
            ai -= v * tws[m];
        }
        Sr[base + (size_t)k * NF + f] = ar;
        Si[base + (size_t)k * NF + f] = ai;
    }
}

// ---------------- K5: qk = S S^T (complex), sigmoid gate, a = g S ----------------
__global__ __launch_bounds__(256) void k_qka(const float* __restrict__ Sr,
                                             const float* __restrict__ Si,
                                             float* __restrict__ Ar,
                                             float* __restrict__ Ai) {
    __shared__ float sr[DM * NF], si[DM * NF];  // 5440 each
    __shared__ float gr[DM * DM], gi[DM * DM];  // 4096 each
    int bn = blockIdx.x;
    int t = threadIdx.x;
    size_t base = (size_t)bn * DM * NF;
    for (int i = t; i < DM * NF; i += 256) { sr[i] = Sr[base + i]; si[i] = Si[base + i]; }
    __syncthreads();
    for (int e = t; e < DM * DM; e += 256) {
        int x = e >> 6, y = e & 63;
        const float* pxr = sr + x * NF;
        const float* pxi = si + x * NF;
        const float* pyr = sr + y * NF;
        const float* pyi = si + y * NF;
        float qr = 0.f, qi = 0.f;
        for (int f = 0; f < NF; ++f) {
            float xr = pxr[f], xi = pxi[f], yr = pyr[f], yi = pyi[f];
            qr += xr * yr - xi * yi;
            qi += xr * yi + xi * yr;
        }
        gr[e] = 1.f / (1.f + __expf(-qr));
        gi[e] = 1.f / (1.f + __expf(-qi));
    }
    __syncthreads();
    for (int e = t; e < DM * NF; e += 256) {
        int x = e / NF, f = e % NF;
        const float* pgr = gr + x * 64;
        const float* pgi = gi + x * 64;
        float ar = 0.f, ai = 0.f;
        for (int y = 0; y < 64; ++y) {
            float syr = sr[y * NF + f], syi = si[y * NF + f];
            float g1 = pgr[y], g2 = pgi[y];
            ar += g1 * syr - g2 * syi;
            ai += g1 * syi + g2 * syr;
        }
        Ar[base + e] = ar;
        Ai[base + e] = ai;
    }
}

// ---------------- K6: complex 1x1 conv (c0) + relu + combine into yfull ----------------
__global__ __launch_bounds__(256) void k_c0(const float* __restrict__ Ar,
                                            const float* __restrict__ Ai,
                                            const float* __restrict__ wr,
                                            const float* __restrict__ wi,
                                            const float* __restrict__ br,
                                            const float* __restrict__ bi,
                                            const float* __restrict__ l0w,
                                            float* __restrict__ yfull) {
    __shared__ float lr[DM * NF], li[DM * NF];
    int b = blockIdx.x >> 6, x = blockIdx.x & 63;
    int t = threadIdx.x;
    for (int i = t; i < DM * NF; i += 256) {
        int ci = i / NF, f = i % NF;
        size_t src = ((size_t)(b * 64 + ci) * 64 + x) * NF + f;
        lr[i] = Ar[src];
        li[i] = Ai[src];
    }
    __syncthreads();
    float w0 = l0w[0], w1 = l0w[1];
    int co = t >> 2, yg = t & 3;
    float accr[22], acci[22];
#pragma unroll
    for (int j = 0; j < 22; ++j) { accr[j] = 0.f; acci[j] = 0.f; }
    for (int ci = 0; ci < 64; ++ci) {
        float wwr = wr[co * 64 + ci], wwi = wi[co * 64 + ci];
        const float* pr = lr + ci * NF;
        const float* pi = li + ci * NF;
#pragma unroll
        for (int j = 0; j < 22; ++j) {
            int f = yg + 4 * j;
            if (f < NF) {
                float xr = pr[f], xi = pi[f];
                accr[j] += xr * wwr - xi * wwi;
                acci[j] += xi * wwr + xr * wwi;
            }
        }
    }
    float bbr = br[co] - bi[co];
    float bbi = br[co] + bi[co];
    size_t obase = ((size_t)(b * 64 + co) * 64 + x) * NF;
    for (int j = 0; j < 22; ++j) {
        int f = yg + 4 * j;
        if (f < NF) {
            float yr = fmaxf(accr[j] + bbr, 0.f);
            float yi = fmaxf(acci[j] + bbi, 0.f);
            yfull[obase + f] = (yr * w0 + yi * w1) * INV3;
        }
    }
}

// ---------------- K-wprep: pack complex conv weights into MFMA A-layout ----------------
// Wt[conv][tap][chunk][m=128][c32=32] bf16; m<64: real-out rows (+wr / -wi),
// m>=64: imag-out rows (+wi / +wr); c32 = 2*ci_local + part.
__global__ __launch_bounds__(256) void k_wprep(const float* __restrict__ cA_wr,
                                               const float* __restrict__ cA_wi,
                                               const float* __restrict__ cB_wr,
                                               const float* __restrict__ cB_wi,
                                               short* __restrict__ wt) {
    int idx = blockIdx.x * 256 + threadIdx.x;
    if (idx >= 8 * 9 * 4 * 128 * 32) return;
    int c32 = idx & 31;
    int m = (idx >> 5) & 127;
    int chunk = (idx >> 12) & 3;
    int tap = (idx >> 14) % 9;
    int conv = idx / (9 * 16384);
    int l = conv >> 2, k1 = (conv >> 1) & 1, ab = conv & 1;
    int ci = chunk * 16 + (c32 >> 1);
    int part = c32 & 1;
    int co = m & 63;
    size_t woff = (((size_t)(l * 2 + k1) * 64 + co) * 64 + ci) * 9 + tap;
    const float* wr = ab ? cB_wr : cA_wr;
    const float* wi = ab ? cB_wi : cA_wi;
    float v;
    if (m < 64) v = part ? -wi[woff] : wr[woff];
    else        v = part ?  wr[woff] : wi[woff];
    wt[idx] = f2bf(v);
}

// ---------------- K7: complex 3x3 dilated conv via MFMA implicit GEMM ----------------
// block = (b, x0). M=128 (real+imag co), N=96 (f, 85 valid), K=1152 over 4 chunks x 9 taps.
// mode 0: write h f32 (bias only); mode 1: relu+combine, accumulate into yfull.
__global__ __launch_bounds__(256, 4) void k_conv3m(const float* __restrict__ in_r,
                                                   const float* __restrict__ in_i,
                                                   const short* __restrict__ wt,
                                                   const float* __restrict__ b_r,
                                                   const float* __restrict__ b_i,
                                                   int K, int mode,
                                                   const float* __restrict__ l0w,
                                                   float* __restrict__ out_r,
                                                   float* __restrict__ out_i) {
    // channel-last LDS tile: [xr 3][fslot 100][c 40(pad, 32 used)] bf16, group-XOR swizzle
    __shared__ __align__(16) short inT[3 * 100 * 40];  // 24000 B
    int b = blockIdx.x >> 6, x0 = blockIdx.x & 63;
    int tid = threadIdx.x;
    int lane = tid & 63, wid = tid >> 6;
    int wrow = wid & 1, wcol = wid >> 1;
    int l15 = lane & 15, g = lane >> 4;

    { int* p = (int*)inT;
      for (int i = tid; i < 6000; i += 256) p[i] = 0; }

    f32x4 acc[4][3];
#pragma unroll
    for (int a = 0; a < 4; ++a)
#pragma unroll
        for (int j = 0; j < 3; ++j) acc[a][j] = f32x4{0.f, 0.f, 0.f, 0.f};

    for (int chunk = 0; chunk < 4; ++chunk) {
        __syncthreads();
        // stage 16 ci x {r,i} x 3 x-rows x 85 f -> LDS (pair-packed b32 writes)
        for (int idx = tid; idx < 48 * 85; idx += 256) {
            int r = idx / 85, f = idx - r * 85;
            int xr = r >> 4, cil = r & 15;
            int xg = x0 + (xr - 1) * K;
            if (xg >= 0 && xg < 64) {
                int ci = chunk * 16 + cil;
                size_t src = ((size_t)(b * 64 + ci) * 64 + xg) * NF + f;
                int lo = f2bf(in_r[src]) & 0xffff;
                int hi = f2bf(in_i[src]);
                int slot = f + 2;
                int c0 = cil * 2;
                int gg = (c0 >> 3) ^ (slot & 3);
                int pos = (gg << 3) + (c0 & 7);
                *(int*)&inT[(xr * 100 + slot) * 40 + pos] = lo | (hi << 16);
            }
        }
        __syncthreads();
#pragma unroll
        for (int u = 0; u < 3; ++u) {
#pragma unroll
            for (int v = 0; v < 3; ++v) {
                int tap = u * 3 + v;
                short8v afr[4];
#pragma unroll
                for (int a = 0; a < 4; ++a) {
                    int tile = (a < 2) ? (wrow * 2 + a) : (wrow * 2 + a + 2);
                    const short* ap = wt + ((((size_t)tap * 4 + chunk) * 8 + tile) * 16 + l15) * 32 + g * 8;
                    afr[a] = *(const short8v*)ap;
                }
                short8v bfr[3];
#pragma unroll
                for (int j = 0; j < 3; ++j) {
                    int fs = (wcol * 3 + j) * 16 + l15 + (v - 1) * K + 2;
                    int gg = g ^ (fs & 3);
                    bfr[j] = *(const short8v*)&inT[(u * 100 + fs) * 40 + gg * 8];
                }
#pragma unroll
                for (int a = 0; a < 4; ++a)
#pragma unroll
                    for (int j = 0; j < 3; ++j)
                        acc[a][j] = __builtin_amdgcn_mfma_f32_16x16x32_bf16(afr[a], bfr[j],
                                                                            acc[a][j], 0, 0, 0);
            }
        }
    }
    float w0 = 0.f, w1 = 0.f;
    if (mode == 1) { w0 = l0w[0]; w1 = l0w[1]; }
#pragma unroll
    for (int a = 0; a < 2; ++a) {
#pragma unroll
        for (int j = 0; j < 3; ++j) {
            int f = (wcol * 3 + j) * 16 + l15;
            if (f < NF) {
#pragma unroll
                for (int reg = 0; reg < 4; ++reg) {
                    int co = (wrow * 2 + a) * 16 + g * 4 + reg;
                    float vr = acc[a][j][reg]     + b_r[co] - b_i[co];
                    float vi = acc[a + 2][j][reg] + b_r[co] + b_i[co];
                    size_t o = ((size_t)(b * 64 + co) * 64 + x0) * NF + f;
                    if (mode == 0) { out_r[o] = vr; out_i[o] = vi; }
                    else out_r[o] += (fmaxf(vr, 0.f) * w0 + fmaxf(vi, 0.f) * w1) * INV3;
                }
            }
        }
    }
}

// ---------------- K8: mean over freq axis + l0 bias ----------------
__global__ __launch_bounds__(256) void k_reduce(const float* __restrict__ yfull,
                                                const float* __restrict__ l0b,
                                                float* __restrict__ y2, int bc) {
    int i = blockIdx.x * 256 + threadIdx.x;
    if (i >= bc * DM * NF) return;
    int f = i % NF;
    int rest = i / NF;
    int n = rest & 63;
    int b = rest >> 6;
    float s = 0.f;
    const float* p = yfull + ((size_t)(b * 64 + n) * 64) * NF + f;
    for (int x = 0; x < 64; ++x) s += p[x * NF];
    y2[i] = s * (1.f / 64.f) + l0b[0];
}

// ---------------- K9: l2 (NF->ALL) + transpose + LayerNorm ----------------
__global__ __launch_bounds__(64) void k_l2ln(const float* __restrict__ y2,
                                             const float* __restrict__ l2w,
                                             const float* __restrict__ l2b,
                                             const float* __restrict__ g,
                                             const float* __restrict__ be,
                                             float* __restrict__ enc, int b0) {
    int bl = blockIdx.x / ALLT;
    int a = blockIdx.x % ALLT;
    int d = threadIdx.x;
    const float* wp = l2w + (size_t)a * NF;
    const float* yp = y2 + (size_t)(bl * 64 + d) * NF;
    float acc = l2b[a];
    for (int f = 0; f < NF; ++f) acc += yp[f] * wp[f];
    float s = acc, s2 = acc * acc;
    for (int m = 32; m >= 1; m >>= 1) { s += __shfl_xor(s, m); s2 += __shfl_xor(s2, m); }
    float mu = s * (1.f / 64.f);
    float var = s2 * (1.f / 64.f) - mu * mu;
    float rs = rsqrtf(var + 1e-5f);
    enc[((size_t)(b0 + bl) * ALLT + a) * DM + d] = (acc - mu) * rs * g[d] + be[d];
}

// ---------------- K10: T[b,ci,j] = sum_hx enc[b,ci,2hx+j-1]*l1w[hx] ----------------
__global__ __launch_bounds__(256) void k_T(const float* __restrict__ enc,
                                           const float* __restrict__ l1w,
                                           float* __restrict__ T) {
    int i = blockIdx.x * 256 + threadIdx.x;
    if (i >= Bt * ALLT * 3) return;
    int j = i % 3;
    int rest = i / 3;
    int ci = rest % ALLT;
    int b = rest / ALLT;
    const float* e = enc + ((size_t)b * ALLT + ci) * DM;
    float s = 0.f;
    for (int hx = 0; hx < 32; ++hx) {
        int p = 2 * hx + j - 1;
        if (p >= 0 && p < DM) s += e[p] * l1w[hx];
    }
    T[i] = s;
}

// ---------------- K11: seq_series[b,co] ----------------
__global__ __launch_bounds__(256) void k_seq(const float* __restrict__ T,
                                             const float* __restrict__ cvw,
                                             const float* __restrict__ cvb,
                                             const float* __restrict__ l1w,
                                             const float* __restrict__ l1b,
                                             float* __restrict__ out) {
    int i = blockIdx.x * 256 + threadIdx.x;
    if (i >= Bt * ALLT) return;
    int co = i % ALLT;
    int b = i / ALLT;
    float sl1 = 0.f;
    for (int hx = 0; hx < 32; ++hx) sl1 += l1w[hx];
    const float* tp = T + (size_t)b * ALLT * 3;
    const float* wp = cvw + (size_t)co * ALLT * 3;
    float s = 0.f;
    for (int q = 0; q < ALLT * 3; ++q) s += tp[q] * wp[q];
    out[i] = s + cvb[co] * sl1 + l1b[0];
}

// ---------------- K12: projection + denorm, last PRED steps ----------------
__global__ __launch_bounds__(256) void k_dec(const float* __restrict__ enc,
                                             const float* __restrict__ pw,
                                             const float* __restrict__ pb,
                                             const float* __restrict__ mean,
                                             const float* __restrict__ stdv,
                                             float* __restrict__ out) {
    int i = blockIdx.x * 256 + threadIdx.x;
    if (i >= Bt * PRED * CIN) return;
    int c = i % CIN;
    int rest = i / CIN;
    int tt = rest % PRED;
    int b = rest / PRED;
    const float* e = enc + ((size_t)b * ALLT + SEQ + tt) * DM;
    const float* w = pw + c * DM;
    float s = pb[c];
    for (int d = 0; d < DM; ++d) s += e[d] * w[d];
    out[i] = s * stdv[b * CIN + c] + mean[b * CIN + c];
}

extern "C" void kernel_launch(void* const* d_in, const int* in_sizes, int n_in,
                              void* d_out, int out_size, void* d_ws, size_t ws_size,
                              hipStream_t stream) {
    (void)in_sizes; (void)n_in; (void)out_size;
    const float* x_enc  = (const float*)d_in[0];
    const float* x_mark = (const float*)d_in[1];
    const float* tok_w  = (const float*)d_in[4];
    const float* temp_w = (const float*)d_in[5];
    const float* pl_w   = (const float*)d_in[6];
    const float* pl_b   = (const float*)d_in[7];
    const float* ln_g   = (const float*)d_in[8];
    const float* ln_b   = (const float*)d_in[9];
    const float* c0_wr  = (const float*)d_in[10];
    const float* c0_wi  = (const float*)d_in[11];
    const float* c0_br  = (const float*)d_in[12];
    const float* c0_bi  = (const float*)d_in[13];
    const float* cA_wr  = (const float*)d_in[14];
    const float* cA_wi  = (const float*)d_in[15];
    const float* cA_br  = (const float*)d_in[16];
    const float* cA_bi  = (const float*)d_in[17];
    const float* cB_wr  = (const float*)d_in[18];
    const float* cB_wi  = (const float*)d_in[19];
    const float* cB_br  = (const float*)d_in[20];
    const float* cB_bi  = (const float*)d_in[21];
    const float* l0_w   = (const float*)d_in[22];
    const float* l0_b   = (const float*)d_in[23];
    const float* l2_w   = (const float*)d_in[24];
    const float* l2_b   = (const float*)d_in[25];
    const float* cv_w   = (const float*)d_in[26];
    const float* cv_b   = (const float*)d_in[27];
    const float* l1_w   = (const float*)d_in[28];
    const float* l1_b   = (const float*)d_in[29];
    const float* proj_w = (const float*)d_in[30];
    const float* proj_b = (const float*)d_in[31];

    float* out0 = (float*)d_out;                    // dec: [32,336,7]
    float* out1 = out0 + (size_t)Bt * PRED * CIN;   // seq_series: [32,672]

    float* ws = (float*)d_ws;
    size_t off = 0;
    float* enc  = ws + off; off += (size_t)Bt * ALLT * DM;   // 1,376,256
    float* enc0 = ws + off; off += (size_t)Bt * SEQ * DM;    // 688,128 (reused as T)
    float* mean = ws + off; off += 256;
    float* stdv = ws + off; off += 256;
    short* wtbuf = (short*)(ws + off); off += (size_t)8 * 9 * 4 * 128 * 32 / 2;  // bf16 packed weights

    const size_t perb = (size_t)DM * NFFT * NF;  // 348,160
    int Bc = 32;
    while (Bc > 1) {
        size_t need = (off + (size_t)Bc * DM * NF + 5 * (size_t)Bc * perb) * sizeof(float);
        if (need <= ws_size) break;
        Bc >>= 1;
    }
    float* y2 = ws + off; off += (size_t)Bc * DM * NF;
    float* Sr = ws + off; off += (size_t)Bc * perb;
    float* Si = ws + off; off += (size_t)Bc * perb;
    float* Ar = ws + off; off += (size_t)Bc * perb;
    float* Ai = ws + off; off += (size_t)Bc * perb;
    float* yfull = ws + off; off += (size_t)Bc * perb;
    float* Hr = Sr;  // reuse: S dead after k_qka
    float* Hi = Si;
    float* Tb = enc0;  // reuse: enc0 dead after k_plin

    k_stats<<<Bt * CIN, 64, 0, stream>>>(x_enc, mean, stdv);
    k_wprep<<<(8 * 9 * 4 * 128 * 32 + 255) / 256, 256, 0, stream>>>(cA_wr, cA_wi, cB_wr, cB_wi,
                                                                    wtbuf);
    k_embed<<<(Bt * SEQ * DM + 255) / 256, 256, 0, stream>>>(x_enc, x_mark, tok_w, temp_w,
                                                             mean, stdv, enc0);
    k_plin<<<(Bt * ALLT * DM + 255) / 256, 256, 0, stream>>>(enc0, pl_w, pl_b, enc);

    const size_t wconv = (size_t)9 * 4 * 128 * 32;
    for (int l = 0; l < 2; ++l) {
        for (int b0 = 0; b0 < Bt; b0 += Bc) {
            k_stft<<<Bc * 64, 256, 0, stream>>>(enc, b0, Sr, Si);
            k_qka<<<Bc * 64, 256, 0, stream>>>(Sr, Si, Ar, Ai);
            k_c0<<<Bc * 64, 256, 0, stream>>>(Ar, Ai, c0_wr + (size_t)l * 4096,
                                              c0_wi + (size_t)l * 4096, c0_br + l * 64,
                                              c0_bi + l * 64, l0_w + l * 2, yfull);
            for (int k = 1; k <= 2; ++k) {
                int convA = l * 4 + (k - 1) * 2;
                size_t boff = ((size_t)l * 2 + (k - 1)) * 64;
                k_conv3m<<<Bc * 64, 256, 0, stream>>>(Ar, Ai, wtbuf + (size_t)convA * wconv,
                                                      cA_br + boff, cA_bi + boff, k, 0,
                                                      l0_w + l * 2, Hr, Hi);
                k_conv3m<<<Bc * 64, 256, 0, stream>>>(Hr, Hi, wtbuf + (size_t)(convA + 1) * wconv,
                                                      cB_br + boff, cB_bi + boff, k, 1,
                                                      l0_w + l * 2, yfull, Hi);
            }
            k_reduce<<<(Bc * DM * NF + 255) / 256, 256, 0, stream>>>(yfull, l0_b + l, y2, Bc);
            k_l2ln<<<Bc * ALLT, 64, 0, stream>>>(y2, l2_w + (size_t)l * ALLT * NF,
                                                 l2_b + (size_t)l * ALLT, ln_g, ln_b, enc, b0);
        }
    }

    k_T<<<(Bt * ALLT * 3 + 255) / 256, 256, 0, stream>>>(enc, l1_w, Tb);
    k_seq<<<(Bt * ALLT + 255) / 256, 256, 0, stream>>>(Tb, cv_w, cv_b, l1_w, l1_b, out1);
    k_dec<<<(Bt * PRED * CIN + 255) / 256, 256, 0, stream>>>(enc, proj_w, proj_b, mean, stdv, out0);
}

// Round 4
// 2447.782 us; speedup vs baseline: 5.1256x; 1.2195x over previous
//
#include <hip/hip_runtime.h>

typedef __attribute__((ext_vector_type(8))) short short8v;
typedef __attribute__((ext_vector_type(4))) float f32x4;
typedef __attribute__((ext_vector_type(16))) float f32x16;

static constexpr int Bt = 32;
static constexpr int SEQ = 336, PRED = 336, CIN = 7, ALLT = 672;
static constexpr int DM = 64, NFFT = 64, HOP = 8, NF = 85;
static constexpr int MARK = 4;
static constexpr float INV3 = 1.0f / 3.0f;

__device__ inline short f2bf(float v) {
    unsigned u = __float_as_uint(v);
    u += 0x7fffu + ((u >> 16) & 1u);   // round-to-nearest-even
    return (short)(u >> 16);
}
__device__ inline float bf2f(short h) {
    return __uint_as_float(((unsigned)(unsigned short)h) << 16);
}

// ---------------- K1: per (b,c) mean / std over time ----------------
__global__ __launch_bounds__(64) void k_stats(const float* __restrict__ x,
                                              float* __restrict__ mean,
                                              float* __restrict__ stdv) {
    int bc = blockIdx.x;              // b*7+c
    int b = bc / CIN, c = bc % CIN;
    int lane = threadIdx.x;
    float s = 0.f, s2 = 0.f;
    for (int t = lane; t < SEQ; t += 64) {
        float v = x[(b * SEQ + t) * CIN + c];
        s += v; s2 += v * v;
    }
    for (int m = 32; m >= 1; m >>= 1) { s += __shfl_xor(s, m); s2 += __shfl_xor(s2, m); }
    if (lane == 0) {
        float mu = s / SEQ;
        float var = s2 / SEQ - mu * mu;
        mean[bc] = mu;
        stdv[bc] = sqrtf(var + 1e-5f);
    }
}

// ---------------- K2: embedding (token conv + temporal + PE) ----------------
__global__ __launch_bounds__(256) void k_embed(const float* __restrict__ x,
                                               const float* __restrict__ mark,
                                               const float* __restrict__ tok_w,
                                               const float* __restrict__ temp_w,
                                               const float* __restrict__ mean,
                                               const float* __restrict__ stdv,
                                               float* __restrict__ enc0) {
    int i = blockIdx.x * 256 + threadIdx.x;
    if (i >= Bt * SEQ * DM) return;
    int d = i & 63;
    int t = (i >> 6) % SEQ;
    int b = i / (SEQ * DM);
    float val = 0.f;
    for (int c = 0; c < CIN; ++c) {
        float mu = mean[b * CIN + c];
        float is = 1.f / stdv[b * CIN + c];
        for (int j = 0; j < 3; ++j) {
            int tt = t + j - 1;
            if (tt < 0) tt += SEQ;
            if (tt >= SEQ) tt -= SEQ;
            float xv = (x[(b * SEQ + tt) * CIN + c] - mu) * is;
            val += xv * tok_w[(d * CIN + c) * 3 + j];
        }
    }
    float mk = 0.f;
    for (int m = 0; m < MARK; ++m) mk += mark[(b * SEQ + t) * MARK + m] * temp_w[d * MARK + m];
    float div = expf(-(float)(d & ~1) * (9.210340371976184f / (float)DM));
    float arg = (float)t * div;
    float pe = (d & 1) ? cosf(arg) : sinf(arg);
    enc0[i] = val + mk + pe;
}

// ---------------- K3: predict_linear (time 336 -> 672) ----------------
__global__ __launch_bounds__(256) void k_plin(const float* __restrict__ enc0,
                                              const float* __restrict__ pl_w,
                                              const float* __restrict__ pl_b,
                                              float* __restrict__ enc) {
    int i = blockIdx.x * 256 + threadIdx.x;
    if (i >= Bt * ALLT * DM) return;
    int d = i & 63;
    int a = (i >> 6) % ALLT;
    int b = i / (ALLT * DM);
    float acc = pl_b[a];
    const float* e0 = enc0 + (size_t)b * SEQ * DM + d;
    const float* w = pl_w + (size_t)a * SEQ;
    for (int t = 0; t < SEQ; ++t) acc += e0[t * DM] * w[t];
    enc[i] = acc;
}

// ---------------- K4: STFT (reflect pad + hann + DFT64, ortho) ----------------
__global__ __launch_bounds__(256) void k_stft(const float* __restrict__ enc, int b0,
                                              float* __restrict__ Sr, float* __restrict__ Si) {
    __shared__ float xp[ALLT + NFFT];   // 736
    __shared__ float twc[64], tws[64];
    __shared__ float xw[NF * 65];       // padded ld=65 (bank-conflict-free)
    int bl = blockIdx.x >> 6;
    int n = blockIdx.x & 63;
    int bg = b0 + bl;
    int t = threadIdx.x;
    for (int i = t; i < ALLT + NFFT; i += 256) {
        int j = i - 32;
        if (j < 0) j = -j;
        if (j > ALLT - 1) j = 2 * (ALLT - 1) - j;
        xp[i] = enc[((size_t)bg * ALLT + j) * DM + n];
    }
    if (t < 64) {
        float ang = (6.283185307179586f / 64.f) * (float)t;
        twc[t] = cosf(ang);
        tws[t] = sinf(ang);
    }
    __syncthreads();
    for (int i = t; i < NF * NFFT; i += 256) {
        int f = i >> 6, tt = i & 63;
        float win = (0.5f - 0.5f * twc[tt]) * 0.125f;  // hann * 1/sqrt(64)
        xw[f * 65 + tt] = xp[f * HOP + tt] * win;
    }
    __syncthreads();
    size_t base = (size_t)(bl * 64 + n) * NFFT * NF;
    for (int i = t; i < NFFT * NF; i += 256) {
        int k = i / NF, f = i % NF;
        float ar = 0.f, ai = 0.f;
        for (int tt = 0; tt < 64; ++tt) {
            float v = xw[f * 65 + tt];
            int m = (k * tt) & 63;
            ar += v * twc[m];
            ai -= v * tws[m];
        }
        Sr[base + (size_t)k * NF + f] = ar;
        Si[base + (size_t)k * NF + f] = ai;
    }
}

// ---------------- K5: qk + sigmoid gate + a = g S, via split-bf16 MFMA ----------------
// block = one (b,n). LDS: row-major hi/lo S arrays [64][104], S^T hi/lo [96][72],
// then g hi/lo arrays [64][72] overlay the dead row arrays in phase 2.
__global__ __launch_bounds__(256) void k_qka_m(const float* __restrict__ Sr,
                                               const float* __restrict__ Si,
                                               float* __restrict__ Ar,
                                               float* __restrict__ Ai) {
    __shared__ __align__(16) short L[54272];  // 108,544 B
    constexpr int SRH = 0, SIH = 6656, SRL = 13312, SIL = 19968;        // [64][104]
    constexpr int STRH = 26624, STRL = 33536, STIH = 40448, STIL = 47360;  // [96][72]
    constexpr int GRH = 0, GRL = 4608, GIH = 9216, GIL = 13824;         // [64][72] overlay
    int bn = blockIdx.x;
    int tid = threadIdx.x;
    int lane = tid & 63, w = tid >> 6;
    int l31 = lane & 31, kg = lane >> 5;
    size_t base = (size_t)bn * (64 * 85);

    // zero pad cols f in [85,96) of the 4 row arrays
    for (int j = tid; j < 64 * 11; j += 256) {
        int x = j / 11, f = 85 + j % 11;
        L[SRH + x * 104 + f] = 0; L[SIH + x * 104 + f] = 0;
        L[SRL + x * 104 + f] = 0; L[SIL + x * 104 + f] = 0;
    }
    // zero ST rows f in [85,96)
    for (int j = tid; j < 11 * 72; j += 256) {
        int f = 85 + j / 72, y = j % 72;
        L[STRH + f * 72 + y] = 0; L[STRL + f * 72 + y] = 0;
        L[STIH + f * 72 + y] = 0; L[STIL + f * 72 + y] = 0;
    }
    // stage: split into bf16 hi/lo, row-major + transposed copies
    for (int i = tid; i < 64 * 85; i += 256) {
        int x = i / 85, f = i - x * 85;
        float vr = Sr[base + i], vi = Si[base + i];
        short rh = f2bf(vr); short rl = f2bf(vr - bf2f(rh));
        short ih = f2bf(vi); short il = f2bf(vi - bf2f(ih));
        L[SRH + x * 104 + f] = rh; L[SRL + x * 104 + f] = rl;
        L[SIH + x * 104 + f] = ih; L[SIL + x * 104 + f] = il;
        L[STRH + f * 72 + x] = rh; L[STRL + f * 72 + x] = rl;
        L[STIH + f * 72 + x] = ih; L[STIL + f * 72 + x] = il;
    }
    __syncthreads();

    // ---- phase 1: P = Sr·Sr^T, Q = Si·Si^T, R = qk_i (split-bf16, 3-term) ----
    int mh = w >> 1, nh = w & 1;
    f32x16 P, Q, R;
#pragma unroll
    for (int r = 0; r < 16; ++r) { P[r] = 0.f; Q[r] = 0.f; R[r] = 0.f; }
#pragma unroll
    for (int f0 = 0; f0 < 96; f0 += 16) {
        int ka = f0 + kg * 8;
        int ra = (mh * 32 + l31) * 104 + ka;
        int rb = (nh * 32 + l31) * 104 + ka;
        short8v a_rh = *(const short8v*)&L[SRH + ra];
        short8v a_rl = *(const short8v*)&L[SRL + ra];
        short8v a_ih = *(const short8v*)&L[SIH + ra];
        short8v a_il = *(const short8v*)&L[SIL + ra];
        short8v b_rh = *(const short8v*)&L[SRH + rb];
        short8v b_rl = *(const short8v*)&L[SRL + rb];
        short8v b_ih = *(const short8v*)&L[SIH + rb];
        short8v b_il = *(const short8v*)&L[SIL + rb];
        P = __builtin_amdgcn_mfma_f32_32x32x16_bf16(a_rh, b_rh, P, 0, 0, 0);
        P = __builtin_amdgcn_mfma_f32_32x32x16_bf16(a_rl, b_rh, P, 0, 0, 0);
        P = __builtin_amdgcn_mfma_f32_32x32x16_bf16(a_rh, b_rl, P, 0, 0, 0);
        Q = __builtin_amdgcn_mfma_f32_32x32x16_bf16(a_ih, b_ih, Q, 0, 0, 0);
        Q = __builtin_amdgcn_mfma_f32_32x32x16_bf16(a_il, b_ih, Q, 0, 0, 0);
        Q = __builtin_amdgcn_mfma_f32_32x32x16_bf16(a_ih, b_il, Q, 0, 0, 0);
        R = __builtin_amdgcn_mfma_f32_32x32x16_bf16(a_rh, b_ih, R, 0, 0, 0);
        R = __builtin_amdgcn_mfma_f32_32x32x16_bf16(a_rl, b_ih, R, 0, 0, 0);
        R = __builtin_amdgcn_mfma_f32_32x32x16_bf16(a_rh, b_il, R, 0, 0, 0);
        R = __builtin_amdgcn_mfma_f32_32x32x16_bf16(a_ih, b_rh, R, 0, 0, 0);
        R = __builtin_amdgcn_mfma_f32_32x32x16_bf16(a_il, b_rh, R, 0, 0, 0);
        R = __builtin_amdgcn_mfma_f32_32x32x16_bf16(a_ih, b_rl, R, 0, 0, 0);
    }
    __syncthreads();   // row arrays dead; g overlays them

    // epilogue: sigmoid -> split-bf16 g arrays
    {
        int y = nh * 32 + l31;
#pragma unroll
        for (int r = 0; r < 16; ++r) {
            int x = mh * 32 + (r & 3) + 8 * (r >> 2) + 4 * kg;
            float gr = 1.f / (1.f + __expf(-(P[r] - Q[r])));
            float gi = 1.f / (1.f + __expf(-R[r]));
            short gh = f2bf(gr); short gl = f2bf(gr - bf2f(gh));
            short jh = f2bf(gi); short jl = f2bf(gi - bf2f(jh));
            L[GRH + x * 72 + y] = gh; L[GRL + x * 72 + y] = gl;
            L[GIH + x * 72 + y] = jh; L[GIL + x * 72 + y] = jl;
        }
    }
    __syncthreads();

    // ---- phase 2: a^T[z,x] = sum_y S[y,z] * g[x,y] (complex, full split) ----
    int mg = w >> 1;             // mg0: m-tiles {0,1}; mg1: m-tile {2}
    int mtA = (mg == 0) ? 0 : 2;
    f32x16 u1A, u2A, u3A, u1B, u2B, u3B;
#pragma unroll
    for (int r = 0; r < 16; ++r) {
        u1A[r] = 0.f; u2A[r] = 0.f; u3A[r] = 0.f;
        u1B[r] = 0.f; u2B[r] = 0.f; u3B[r] = 0.f;
    }
#pragma unroll
    for (int y0 = 0; y0 < 64; y0 += 16) {
        int kb = y0 + kg * 8;
        int gb = (nh * 32 + l31) * 72 + kb;
        short8v bgrh = *(const short8v*)&L[GRH + gb];
        short8v bgrl = *(const short8v*)&L[GRL + gb];
        short8v bgih = *(const short8v*)&L[GIH + gb];
        short8v bgil = *(const short8v*)&L[GIL + gb];
        {
            int sa = (mtA * 32 + l31) * 72 + kb;
            short8v arh = *(const short8v*)&L[STRH + sa];
            short8v arl = *(const short8v*)&L[STRL + sa];
            short8v aih = *(const short8v*)&L[STIH + sa];
            short8v ail = *(const short8v*)&L[STIL + sa];
            u1A = __builtin_amdgcn_mfma_f32_32x32x16_bf16(arh, bgrh, u1A, 0, 0, 0);
            u1A = __builtin_amdgcn_mfma_f32_32x32x16_bf16(arl, bgrh, u1A, 0, 0, 0);
            u1A = __builtin_amdgcn_mfma_f32_32x32x16_bf16(arh, bgrl, u1A, 0, 0, 0);
            u2A = __builtin_amdgcn_mfma_f32_32x32x16_bf16(aih, bgih, u2A, 0, 0, 0);
            u2A = __builtin_amdgcn_mfma_f32_32x32x16_bf16(ail, bgih, u2A, 0, 0, 0);
            u2A = __builtin_amdgcn_mfma_f32_32x32x16_bf16(aih, bgil, u2A, 0, 0, 0);
            u3A = __builtin_amdgcn_mfma_f32_32x32x16_bf16(aih, bgrh, u3A, 0, 0, 0);
            u3A = __builtin_amdgcn_mfma_f32_32x32x16_bf16(ail, bgrh, u3A, 0, 0, 0);
            u3A = __builtin_amdgcn_mfma_f32_32x32x16_bf16(aih, bgrl, u3A, 0, 0, 0);
            u3A = __builtin_amdgcn_mfma_f32_32x32x16_bf16(arh, bgih, u3A, 0, 0, 0);
            u3A = __builtin_amdgcn_mfma_f32_32x32x16_bf16(arl, bgih, u3A, 0, 0, 0);
            u3A = __builtin_amdgcn_mfma_f32_32x32x16_bf16(arh, bgil, u3A, 0, 0, 0);
        }
        if (mg == 0) {
            int sa = (1 * 32 + l31) * 72 + kb;
            short8v arh = *(const short8v*)&L[STRH + sa];
            short8v arl = *(const short8v*)&L[STRL + sa];
            short8v aih = *(const short8v*)&L[STIH + sa];
            short8v ail = *(const short8v*)&L[STIL + sa];
            u1B = __builtin_amdgcn_mfma_f32_32x32x16_bf16(arh, bgrh, u1B, 0, 0, 0);
            u1B = __builtin_amdgcn_mfma_f32_32x32x16_bf16(arl, bgrh, u1B, 0, 0, 0);
            u1B = __builtin_amdgcn_mfma_f32_32x32x16_bf16(arh, bgrl, u1B, 0, 0, 0);
            u2B = __builtin_amdgcn_mfma_f32_32x32x16_bf16(aih, bgih, u2B, 0, 0, 0);
            u2B = __builtin_amdgcn_mfma_f32_32x32x16_bf16(ail, bgih, u2B, 0, 0, 0);
            u2B = __builtin_amdgcn_mfma_f32_32x32x16_bf16(aih, bgil, u2B, 0, 0, 0);
            u3B = __builtin_amdgcn_mfma_f32_32x32x16_bf16(aih, bgrh, u3B, 0, 0, 0);
            u3B = __builtin_amdgcn_mfma_f32_32x32x16_bf16(ail, bgrh, u3B, 0, 0, 0);
            u3B = __builtin_amdgcn_mfma_f32_32x32x16_bf16(aih, bgrl, u3B, 0, 0, 0);
            u3B = __builtin_amdgcn_mfma_f32_32x32x16_bf16(arh, bgih, u3B, 0, 0, 0);
            u3B = __builtin_amdgcn_mfma_f32_32x32x16_bf16(arl, bgih, u3B, 0, 0, 0);
            u3B = __builtin_amdgcn_mfma_f32_32x32x16_bf16(arh, bgil, u3B, 0, 0, 0);
        }
    }
    // store: ar = u1 - u2, ai = u3; D[m=z, n=x] -> A[(bn)*5440 + x*85 + z]
    {
        int x2 = nh * 32 + l31;
#pragma unroll
        for (int r = 0; r < 16; ++r) {
            int z = mtA * 32 + (r & 3) + 8 * (r >> 2) + 4 * kg;
            if (z < 85) {
                Ar[base + x2 * 85 + z] = u1A[r] - u2A[r];
                Ai[base + x2 * 85 + z] = u3A[r];
            }
        }
        if (mg == 0) {
#pragma unroll
            for (int r = 0; r < 16; ++r) {
                int z = 32 + (r & 3) + 8 * (r >> 2) + 4 * kg;
                Ar[base + x2 * 85 + z] = u1B[r] - u2B[r];
                Ai[base + x2 * 85 + z] = u3B[r];
            }
        }
    }
}

// ---------------- K6: complex 1x1 conv (c0) + relu + combine into yfull ----------------
__global__ __launch_bounds__(256) void k_c0(const float* __restrict__ Ar,
                                            const float* __restrict__ Ai,
                                            const float* __restrict__ wr,
                                            const float* __restrict__ wi,
                                            const float* __restrict__ br,
                                            const float* __restrict__ bi,
                                            const float* __restrict__ l0w,
                                            float* __restrict__ yfull) {
    __shared__ float lr[DM * NF], li[DM * NF];
    int b = blockIdx.x >> 6, x = blockIdx.x & 63;
    int t = threadIdx.x;
    for (int i = t; i < DM * NF; i += 256) {
        int ci = i / NF, f = i % NF;
        size_t src = ((size_t)(b * 64 + ci) * 64 + x) * NF + f;
        lr[i] = Ar[src];
        li[i] = Ai[src];
    }
    __syncthreads();
    float w0 = l0w[0], w1 = l0w[1];
    int co = t >> 2, yg = t & 3;
    float accr[22], acci[22];
#pragma unroll
    for (int j = 0; j < 22; ++j) { accr[j] = 0.f; acci[j] = 0.f; }
    for (int ci = 0; ci < 64; ++ci) {
        float wwr = wr[co * 64 + ci], wwi = wi[co * 64 + ci];
        const float* pr = lr + ci * NF;
        const float* pi = li + ci * NF;
#pragma unroll
        for (int j = 0; j < 22; ++j) {
            int f = yg + 4 * j;
            if (f < NF) {
                float xr = pr[f], xi = pi[f];
                accr[j] += xr * wwr - xi * wwi;
                acci[j] += xi * wwr + xr * wwi;
            }
        }
    }
    float bbr = br[co] - bi[co];
    float bbi = br[co] + bi[co];
    size_t obase = ((size_t)(b * 64 + co) * 64 + x) * NF;
    for (int j = 0; j < 22; ++j) {
        int f = yg + 4 * j;
        if (f < NF) {
            float yr = fmaxf(accr[j] + bbr, 0.f);
            float yi = fmaxf(acci[j] + bbi, 0.f);
            yfull[obase + f] = (yr * w0 + yi * w1) * INV3;
        }
    }
}

// ---------------- K-wprep: pack complex conv weights into MFMA A-layout ----------------
__global__ __launch_bounds__(256) void k_wprep(const float* __restrict__ cA_wr,
                                               const float* __restrict__ cA_wi,
                                               const float* __restrict__ cB_wr,
                                               const float* __restrict__ cB_wi,
                                               short* __restrict__ wt) {
    int idx = blockIdx.x * 256 + threadIdx.x;
    if (idx >= 8 * 9 * 4 * 128 * 32) return;
    int c32 = idx & 31;
    int m = (idx >> 5) & 127;
    int chunk = (idx >> 12) & 3;
    int tap = (idx >> 14) % 9;
    int conv = idx / (9 * 16384);
    int l = conv >> 2, k1 = (conv >> 1) & 1, ab = conv & 1;
    int ci = chunk * 16 + (c32 >> 1);
    int part = c32 & 1;
    int co = m & 63;
    size_t woff = (((size_t)(l * 2 + k1) * 64 + co) * 64 + ci) * 9 + tap;
    const float* wr = ab ? cB_wr : cA_wr;
    const float* wi = ab ? cB_wi : cA_wi;
    float v;
    if (m < 64) v = part ? -wi[woff] : wr[woff];
    else        v = part ?  wr[woff] : wi[woff];
    wt[idx] = f2bf(v);
}

// ---------------- K7: complex 3x3 dilated conv via MFMA implicit GEMM ----------------
__global__ __launch_bounds__(256, 4) void k_conv3m(const float* __restrict__ in_r,
                                                   const float* __restrict__ in_i,
                                                   const short* __restrict__ wt,
                                                   const float* __restrict__ b_r,
                                                   const float* __restrict__ b_i,
                                                   int K, int mode,
                                                   const float* __restrict__ l0w,
                                                   float* __restrict__ out_r,
                                                   float* __restrict__ out_i) {
    __shared__ __align__(16) short inT[3 * 100 * 40];  // 24000 B
    int b = blockIdx.x >> 6, x0 = blockIdx.x & 63;
    int tid = threadIdx.x;
    int lane = tid & 63, wid = tid >> 6;
    int wrow = wid & 1, wcol = wid >> 1;
    int l15 = lane & 15, g = lane >> 4;

    { int* p = (int*)inT;
      for (int i = tid; i < 6000; i += 256) p[i] = 0; }

    f32x4 acc[4][3];
#pragma unroll
    for (int a = 0; a < 4; ++a)
#pragma unroll
        for (int j = 0; j < 3; ++j) acc[a][j] = f32x4{0.f, 0.f, 0.f, 0.f};

    for (int chunk = 0; chunk < 4; ++chunk) {
        __syncthreads();
        for (int idx = tid; idx < 48 * 85; idx += 256) {
            int r = idx / 85, f = idx - r * 85;
            int xr = r >> 4, cil = r & 15;
            int xg = x0 + (xr - 1) * K;
            if (xg >= 0 && xg < 64) {
                int ci = chunk * 16 + cil;
                size_t src = ((size_t)(b * 64 + ci) * 64 + xg) * NF + f;
                int lo = f2bf(in_r[src]) & 0xffff;
                int hi = f2bf(in_i[src]);
                int slot = f + 2;
                int c0 = cil * 2;
                int gg = (c0 >> 3) ^ (slot & 3);
                int pos = (gg << 3) + (c0 & 7);
                *(int*)&inT[(xr * 100 + slot) * 40 + pos] = lo | (hi << 16);
            }
        }
        __syncthreads();
#pragma unroll
        for (int u = 0; u < 3; ++u) {
#pragma unroll
            for (int v = 0; v < 3; ++v) {
                int tap = u * 3 + v;
                short8v afr[4];
#pragma unroll
                for (int a = 0; a < 4; ++a) {
                    int tile = (a < 2) ? (wrow * 2 + a) : (wrow * 2 + a + 2);
                    const short* ap = wt + ((((size_t)tap * 4 + chunk) * 8 + tile) * 16 + l15) * 32 + g * 8;
                    afr[a] = *(const short8v*)ap;
                }
                short8v bfr[3];
#pragma unroll
                for (int j = 0; j < 3; ++j) {
                    int fs = (wcol * 3 + j) * 16 + l15 + (v - 1) * K + 2;
                    int gg = g ^ (fs & 3);
                    bfr[j] = *(const short8v*)&inT[(u * 100 + fs) * 40 + gg * 8];
                }
#pragma unroll
                for (int a = 0; a < 4; ++a)
#pragma unroll
                    for (int j = 0; j < 3; ++j)
                        acc[a][j] = __builtin_amdgcn_mfma_f32_16x16x32_bf16(afr[a], bfr[j],
                                                                            acc[a][j], 0, 0, 0);
            }
        }
    }
    float w0 = 0.f, w1 = 0.f;
    if (mode == 1) { w0 = l0w[0]; w1 = l0w[1]; }
#pragma unroll
    for (int a = 0; a < 2; ++a) {
#pragma unroll
        for (int j = 0; j < 3; ++j) {
            int f = (wcol * 3 + j) * 16 + l15;
            if (f < NF) {
#pragma unroll
                for (int reg = 0; reg < 4; ++reg) {
                    int co = (wrow * 2 + a) * 16 + g * 4 + reg;
                    float vr = acc[a][j][reg]     + b_r[co] - b_i[co];
                    float vi = acc[a + 2][j][reg] + b_r[co] + b_i[co];
                    size_t o = ((size_t)(b * 64 + co) * 64 + x0) * NF + f;
                    if (mode == 0) { out_r[o] = vr; out_i[o] = vi; }
                    else out_r[o] += (fmaxf(vr, 0.f) * w0 + fmaxf(vi, 0.f) * w1) * INV3;
                }
            }
        }
    }
}

// ---------------- K8: mean over freq axis + l0 bias ----------------
__global__ __launch_bounds__(256) void k_reduce(const float* __restrict__ yfull,
                                                const float* __restrict__ l0b,
                                                float* __restrict__ y2, int bc) {
    int i = blockIdx.x * 256 + threadIdx.x;
    if (i >= bc * DM * NF) return;
    int f = i % NF;
    int rest = i / NF;
    int n = rest & 63;
    int b = rest >> 6;
    float s = 0.f;
    const float* p = yfull + ((size_t)(b * 64 + n) * 64) * NF + f;
    for (int x = 0; x < 64; ++x) s += p[x * NF];
    y2[i] = s * (1.f / 64.f) + l0b[0];
}

// ---------------- K9: l2 (NF->ALL) + transpose + LayerNorm ----------------
__global__ __launch_bounds__(64) void k_l2ln(const float* __restrict__ y2,
                                             const float* __restrict__ l2w,
                                             const float* __restrict__ l2b,
                                             const float* __restrict__ g,
                                             const float* __restrict__ be,
                                             float* __restrict__ enc, int b0) {
    int bl = blockIdx.x / ALLT;
    int a = blockIdx.x % ALLT;
    int d = threadIdx.x;
    const float* wp = l2w + (size_t)a * NF;
    const float* yp = y2 + (size_t)(bl * 64 + d) * NF;
    float acc = l2b[a];
    for (int f = 0; f < NF; ++f) acc += yp[f] * wp[f];
    float s = acc, s2 = acc * acc;
    for (int m = 32; m >= 1; m >>= 1) { s += __shfl_xor(s, m); s2 += __shfl_xor(s2, m); }
    float mu = s * (1.f / 64.f);
    float var = s2 * (1.f / 64.f) - mu * mu;
    float rs = rsqrtf(var + 1e-5f);
    enc[((size_t)(b0 + bl) * ALLT + a) * DM + d] = (acc - mu) * rs * g[d] + be[d];
}

// ---------------- K10: T[b,ci,j] = sum_hx enc[b,ci,2hx+j-1]*l1w[hx] ----------------
__global__ __launch_bounds__(256) void k_T(const float* __restrict__ enc,
                                           const float* __restrict__ l1w,
                                           float* __restrict__ T) {
    int i = blockIdx.x * 256 + threadIdx.x;
    if (i >= Bt * ALLT * 3) return;
    int j = i % 3;
    int rest = i / 3;
    int ci = rest % ALLT;
    int b = rest / ALLT;
    const float* e = enc + ((size_t)b * ALLT + ci) * DM;
    float s = 0.f;
    for (int hx = 0; hx < 32; ++hx) {
        int p = 2 * hx + j - 1;
        if (p >= 0 && p < DM) s += e[p] * l1w[hx];
    }
    T[i] = s;
}

// ---------------- K11: seq_series[b,co] ----------------
__global__ __launch_bounds__(256) void k_seq(const float* __restrict__ T,
                                             const float* __restrict__ cvw,
                                             const float* __restrict__ cvb,
                                             const float* __restrict__ l1w,
                                             const float* __restrict__ l1b,
                                             float* __restrict__ out) {
    int i = blockIdx.x * 256 + threadIdx.x;
    if (i >= Bt * ALLT) return;
    int co = i % ALLT;
    int b = i / ALLT;
    float sl1 = 0.f;
    for (int hx = 0; hx < 32; ++hx) sl1 += l1w[hx];
    const float* tp = T + (size_t)b * ALLT * 3;
    const float* wp = cvw + (size_t)co * ALLT * 3;
    float s = 0.f;
    for (int q = 0; q < ALLT * 3; ++q) s += tp[q] * wp[q];
    out[i] = s + cvb[co] * sl1 + l1b[0];
}

// ---------------- K12: projection + denorm, last PRED steps ----------------
__global__ __launch_bounds__(256) void k_dec(const float* __restrict__ enc,
                                             const float* __restrict__ pw,
                                             const float* __restrict__ pb,
                                             const float* __restrict__ mean,
                                             const float* __restrict__ stdv,
                                             float* __restrict__ out) {
    int i = blockIdx.x * 256 + threadIdx.x;
    if (i >= Bt * PRED * CIN) return;
    int c = i % CIN;
    int rest = i / CIN;
    int tt = rest % PRED;
    int b = rest / PRED;
    const float* e = enc + ((size_t)b * ALLT + SEQ + tt) * DM;
    const float* w = pw + c * DM;
    float s = pb[c];
    for (int d = 0; d < DM; ++d) s += e[d] * w[d];
    out[i] = s * stdv[b * CIN + c] + mean[b * CIN + c];
}

extern "C" void kernel_launch(void* const* d_in, const int* in_sizes, int n_in,
                              void* d_out, int out_size, void* d_ws, size_t ws_size,
                              hipStream_t stream) {
    (void)in_sizes; (void)n_in; (void)out_size;
    const float* x_enc  = (const float*)d_in[0];
    const float* x_mark = (const float*)d_in[1];
    const float* tok_w  = (const float*)d_in[4];
    const float* temp_w = (const float*)d_in[5];
    const float* pl_w   = (const float*)d_in[6];
    const float* pl_b   = (const float*)d_in[7];
    const float* ln_g   = (const float*)d_in[8];
    const float* ln_b   = (const float*)d_in[9];
    const float* c0_wr  = (const float*)d_in[10];
    const float* c0_wi  = (const float*)d_in[11];
    const float* c0_br  = (const float*)d_in[12];
    const float* c0_bi  = (const float*)d_in[13];
    const float* cA_wr  = (const float*)d_in[14];
    const float* cA_wi  = (const float*)d_in[15];
    const float* cA_br  = (const float*)d_in[16];
    const float* cA_bi  = (const float*)d_in[17];
    const float* cB_wr  = (const float*)d_in[18];
    const float* cB_wi  = (const float*)d_in[19];
    const float* cB_br  = (const float*)d_in[20];
    const float* cB_bi  = (const float*)d_in[21];
    const float* l0_w   = (const float*)d_in[22];
    const float* l0_b   = (const float*)d_in[23];
    const float* l2_w   = (const float*)d_in[24];
    const float* l2_b   = (const float*)d_in[25];
    const float* cv_w   = (const float*)d_in[26];
    const float* cv_b   = (const float*)d_in[27];
    const float* l1_w   = (const float*)d_in[28];
    const float* l1_b   = (const float*)d_in[29];
    const float* proj_w = (const float*)d_in[30];
    const float* proj_b = (const float*)d_in[31];

    float* out0 = (float*)d_out;                    // dec: [32,336,7]
    float* out1 = out0 + (size_t)Bt * PRED * CIN;   // seq_series: [32,672]

    float* ws = (float*)d_ws;
    size_t off = 0;
    float* enc  = ws + off; off += (size_t)Bt * ALLT * DM;   // 1,376,256
    float* enc0 = ws + off; off += (size_t)Bt * SEQ * DM;    // 688,128 (reused as T)
    float* mean = ws + off; off += 256;
    float* stdv = ws + off; off += 256;
    short* wtbuf = (short*)(ws + off); off += (size_t)8 * 9 * 4 * 128 * 32 / 2;  // bf16 packed weights

    const size_t perb = (size_t)DM * NFFT * NF;  // 348,160
    int Bc = 32;
    while (Bc > 1) {
        size_t need = (off + (size_t)Bc * DM * NF + 5 * (size_t)Bc * perb) * sizeof(float);
        if (need <= ws_size) break;
        Bc >>= 1;
    }
    float* y2 = ws + off; off += (size_t)Bc * DM * NF;
    float* Sr = ws + off; off += (size_t)Bc * perb;
    float* Si = ws + off; off += (size_t)Bc * perb;
    float* Ar = ws + off; off += (size_t)Bc * perb;
    float* Ai = ws + off; off += (size_t)Bc * perb;
    float* yfull = ws + off; off += (size_t)Bc * perb;
    float* Hr = Sr;  // reuse: S dead after k_qka_m
    float* Hi = Si;
    float* Tb = enc0;  // reuse: enc0 dead after k_plin

    k_stats<<<Bt * CIN, 64, 0, stream>>>(x_enc, mean, stdv);
    k_wprep<<<(8 * 9 * 4 * 128 * 32 + 255) / 256, 256, 0, stream>>>(cA_wr, cA_wi, cB_wr, cB_wi,
                                                                    wtbuf);
    k_embed<<<(Bt * SEQ * DM + 255) / 256, 256, 0, stream>>>(x_enc, x_mark, tok_w, temp_w,
                                                             mean, stdv, enc0);
    k_plin<<<(Bt * ALLT * DM + 255) / 256, 256, 0, stream>>>(enc0, pl_w, pl_b, enc);

    const size_t wconv = (size_t)9 * 4 * 128 * 32;
    for (int l = 0; l < 2; ++l) {
        for (int b0 = 0; b0 < Bt; b0 += Bc) {
            k_stft<<<Bc * 64, 256, 0, stream>>>(enc, b0, Sr, Si);
            k_qka_m<<<Bc * 64, 256, 0, stream>>>(Sr, Si, Ar, Ai);
            k_c0<<<Bc * 64, 256, 0, stream>>>(Ar, Ai, c0_wr + (size_t)l * 4096,
                                              c0_wi + (size_t)l * 4096, c0_br + l * 64,
                                              c0_bi + l * 64, l0_w + l * 2, yfull);
            for (int k = 1; k <= 2; ++k) {
                int convA = l * 4 + (k - 1) * 2;
                size_t boff = ((size_t)l * 2 + (k - 1)) * 64;
                k_conv3m<<<Bc * 64, 256, 0, stream>>>(Ar, Ai, wtbuf + (size_t)convA * wconv,
                                                      cA_br + boff, cA_bi + boff, k, 0,
                                                      l0_w + l * 2, Hr, Hi);
                k_conv3m<<<Bc * 64, 256, 0, stream>>>(Hr, Hi, wtbuf + (size_t)(convA + 1) * wconv,
                                                      cB_br + boff, cB_bi + boff, k, 1,
                                                      l0_w + l * 2, yfull, Hi);
            }
            k_reduce<<<(Bc * DM * NF + 255) / 256, 256, 0, stream>>>(yfull, l0_b + l, y2, Bc);
            k_l2ln<<<Bc * ALLT, 64, 0, stream>>>(y2, l2_w + (size_t)l * ALLT * NF,
                                                 l2_b + (size_t)l * ALLT, ln_g, ln_b, enc, b0);
        }
    }

    k_T<<<(Bt * ALLT * 3 + 255) / 256, 256, 0, stream>>>(enc, l1_w, Tb);
    k_seq<<<(Bt * ALLT + 255) / 256, 256, 0, stream>>>(Tb, cv_w, cv_b, l1_w, l1_b, out1);
    k_dec<<<(Bt * PRED * CIN + 255) / 256, 256, 0, stream>>>(enc, proj_w, proj_b, mean, stdv, out0);
}